// Round 7
// baseline (62.075 us; speedup 1.0000x reference)
//
#include <hip/hip_runtime.h>

#define NN 65536
#define PP 128
#define EPSV 1e-8f
#define BIGV 999.0f
#define MAGIC 0x7FEDC123

typedef float f32x4 __attribute__((ext_vector_type(4)));

// ---- output float offsets (return-order flattening) ----
#define O_RMS   0
#define O_RMSQ  128
#define O_NP    256
#define O_NN    384
#define O_RMSG  1024
#define O_RMSQG 1025
#define O_NG    1026
#define O_NNG   1027
#define O_DB    1032
#define O_NNODE 1033
#define O_DIST  66569
#define O_BEL   (66569 + 8388608)

// ---- workspace float offsets ----
#define W_BS   0                  // 64 x 8: A,B0,B1,B2,Cq,Sq,Sxx,(pad)
#define W_PP   512                // 64 x 640: sx0[128],sx1,sx2,sxx,cnt
#define W_CNT  41472              // 64 ints: per-block cond count
#define W_FLG  41536              // 64 ints: done flags
#define W_CL4  303680             // float4 x 65536: compacted x0,x1,x2,ic

__device__ inline float wred(float v) {
#pragma unroll
  for (int o = 32; o > 0; o >>= 1) v += __shfl_down(v, o, 64);
  return v;
}

__device__ inline void t5ins(float t[5], float v) {
  if (v < t[4]) {
    t[4] = v;
#pragma unroll
    for (int k = 4; k > 0; --k)
      if (t[k] < t[k - 1]) { float tm = t[k]; t[k] = t[k - 1]; t[k - 1] = tm; }
  }
}

__device__ inline void merge5(const float* a, const float* b, float* o) {
  int i = 0, j = 0;
#pragma unroll
  for (int k = 0; k < 5; ++k) {
    float av = a[i], bv = b[j];
    if (av <= bv) { o[k] = av; ++i; } else { o[k] = bv; ++j; }
  }
}

__device__ inline void spin_flags(const int* flg, int tid) {
  if (tid < 64) {
    while (__hip_atomic_load(flg + tid, __ATOMIC_ACQUIRE,
                             __HIP_MEMORY_SCOPE_AGENT) != MAGIC)
      __builtin_amdgcn_s_sleep(2);
  }
  __syncthreads();
}

// Single fused kernel, 1218 blocks (NO occupancy clamp — R5's (256,5) caused
// VGPR=40 spills → 6.5x slowdown):
//   [0,64)      stats + (phase2 after flag-sync) N_node
//   [64,1088)   edge writes (independent of everything)
//   [1088,1217) top5 rows 0..128 (dispatched last; spin exits immediately)
//   1217        finalize
__global__ __launch_bounds__(256) void gA(const float* __restrict__ x,
                                          const float* __restrict__ q,
                                          const float* __restrict__ ic,
                                          const int* __restrict__ par,
                                          const float* __restrict__ mx,
                                          const float* __restrict__ mq,
                                          float* __restrict__ ws,
                                          float* __restrict__ out) {
  __shared__ __align__(16) float sbuf[1344];
  int tid = threadIdx.x, bx = blockIdx.x;
  int* flg = (int*)ws + W_FLG;
  if (bx < 64) {
    // ---- stat path ----
    float* ps = sbuf;                   // 640
    float* wsum = sbuf + 640;           // 4x8
    int* lcnt = (int*)(sbuf + 672);     // 1
    int b = bx;
    for (int i = tid; i < 640; i += 256) ps[i] = 0.f;
    if (tid == 0) *lcnt = 0;
    __syncthreads();
    float A = 0.f, B0 = 0.f, B1 = 0.f, B2 = 0.f, Cq = 0.f, Sq = 0.f, Sxx = 0.f;
    float4* cl4 = (float4*)(ws + W_CL4);
    int base = b * 1024;
    int pas[4];
#pragma unroll
    for (int it = 0; it < 4; ++it) {
      int n = base + it * 256 + tid;
      float x0 = x[3 * n], x1 = x[3 * n + 1], x2 = x[3 * n + 2];
      float qn = q[n], icn = ic[n];
      int pa = par[n];
      pas[it] = pa;
      float xx = fmaf(x0, x0, fmaf(x1, x1, x2 * x2));
      float q2 = qn * qn;
      A = fmaf(q2, xx, A); B0 = fmaf(q2, x0, B0);
      B1 = fmaf(q2, x1, B1); B2 = fmaf(q2, x2, B2);
      Cq += q2; Sq += qn; Sxx += xx;
      atomicAdd(&ps[pa], x0);
      atomicAdd(&ps[128 + pa], x1);
      atomicAdd(&ps[256 + pa], x2);
      atomicAdd(&ps[384 + pa], xx);
      atomicAdd(&ps[512 + pa], 1.0f);
      if (icn != 0.0f) {
        int loc = atomicAdd(lcnt, 1);
        cl4[base + loc] = make_float4(x0, x1, x2, icn);
      }
    }
    A = wred(A); B0 = wred(B0); B1 = wred(B1); B2 = wred(B2);
    Cq = wred(Cq); Sq = wred(Sq); Sxx = wred(Sxx);
    int w = tid >> 6, lane = tid & 63;
    if (lane == 0) {
      wsum[w * 8 + 0] = A; wsum[w * 8 + 1] = B0; wsum[w * 8 + 2] = B1;
      wsum[w * 8 + 3] = B2; wsum[w * 8 + 4] = Cq; wsum[w * 8 + 5] = Sq;
      wsum[w * 8 + 6] = Sxx;
    }
    __syncthreads();
    if (tid < 7)
      ws[W_BS + b * 8 + tid] =
          wsum[tid] + wsum[8 + tid] + wsum[16 + tid] + wsum[24 + tid];
    if (tid == 0) ((int*)ws)[W_CNT + b] = *lcnt;
    for (int i = tid; i < 640; i += 256) ws[W_PP + b * 640 + i] = ps[i];
    __threadfence();
    __syncthreads();
    if (tid == 0)
      __hip_atomic_store(flg + b, MAGIC, __ATOMIC_RELEASE, __HIP_MEMORY_SCOPE_AGENT);
    // ---- phase 2: N_node for this block's node range ----
    spin_flags(flg, tid);
    float* snp = sbuf;   // reuse
    if (tid < 128) {
      float s = 0.f;
      for (int b2 = 0; b2 < 64; ++b2) s += ws[W_PP + b2 * 640 + 512 + tid];
      snp[tid] = s;
    }
    __syncthreads();
#pragma unroll
    for (int it = 0; it < 4; ++it) {
      int n = base + it * 256 + tid;
      __builtin_nontemporal_store(snp[pas[it]], out + O_NNODE + n);
    }
  } else if (bx < 1088) {
    // ---- edge path: direct global reads (R6-proven) ----
    float* smx = sbuf;   // 24
    int e = bx - 64;
    int ey = e >> 6, ex = e & 63;
    int p0 = ey * 8;
    if (tid < 24) smx[tid] = mx[p0 * 3 + tid];
    __syncthreads();
    int v = ex * 256 + tid;
    if (v < 16383) {
      int n0 = 3 + 4 * v;
      float xv[12];
#pragma unroll
      for (int j = 0; j < 12; ++j) xv[j] = x[3 * n0 + j];
      int pa0 = par[n0], pa1 = par[n0 + 1], pa2 = par[n0 + 2], pa3 = par[n0 + 3];
#pragma unroll
      for (int pi = 0; pi < 8; ++pi) {
        int p = p0 + pi;
        float m0 = smx[3 * pi], m1 = smx[3 * pi + 1], m2 = smx[3 * pi + 2];
        f32x4 d, bl;
        float d0, d1, d2;
        d0 = xv[0] - m0; d1 = xv[1] - m1; d2 = xv[2] - m2;
        d.x = sqrtf(fmaf(d0, d0, fmaf(d1, d1, d2 * d2)));
        d0 = xv[3] - m0; d1 = xv[4] - m1; d2 = xv[5] - m2;
        d.y = sqrtf(fmaf(d0, d0, fmaf(d1, d1, d2 * d2)));
        d0 = xv[6] - m0; d1 = xv[7] - m1; d2 = xv[8] - m2;
        d.z = sqrtf(fmaf(d0, d0, fmaf(d1, d1, d2 * d2)));
        d0 = xv[9] - m0; d1 = xv[10] - m1; d2 = xv[11] - m2;
        d.w = sqrtf(fmaf(d0, d0, fmaf(d1, d1, d2 * d2)));
        bl.x = (pa0 == p) ? 1.f : 0.f; bl.y = (pa1 == p) ? 1.f : 0.f;
        bl.z = (pa2 == p) ? 1.f : 0.f; bl.w = (pa3 == p) ? 1.f : 0.f;
        size_t ro = (size_t)p * NN + n0;
        __builtin_nontemporal_store(d,  (f32x4*)(out + O_DIST + ro));
        __builtin_nontemporal_store(bl, (f32x4*)(out + O_BEL + ro));
      }
    } else if (v == 16383) {
      int ns[4] = {0, 1, 2, 65535};
#pragma unroll
      for (int k = 0; k < 4; ++k) {
        int n = ns[k];
        float x0 = x[3 * n], x1 = x[3 * n + 1], x2 = x[3 * n + 2];
        int pa = par[n];
#pragma unroll
        for (int pi = 0; pi < 8; ++pi) {
          int p = p0 + pi;
          float m0 = smx[3 * pi], m1 = smx[3 * pi + 1], m2 = smx[3 * pi + 2];
          float d0 = x0 - m0, d1 = x1 - m1, d2 = x2 - m2;
          float dd = sqrtf(fmaf(d0, d0, fmaf(d1, d1, d2 * d2)));
          size_t ro = (size_t)p * NN + n;
          __builtin_nontemporal_store(dd, out + O_DIST + ro);
          __builtin_nontemporal_store((pa == p) ? 1.f : 0.f, out + O_BEL + ro);
        }
      }
    }
  } else {
    int r = bx - 1088;
    spin_flags(flg, tid);
    if (r < 129) {
      // ---- top5 ----
      int* cnts = (int*)sbuf;         // 64
      float* sl = sbuf + 64;          // 1280
      float m0 = 0.f, m1 = 0.f, m2 = 0.f;
      if (r < 128) { m0 = mx[3 * r]; m1 = mx[3 * r + 1]; m2 = mx[3 * r + 2]; }
      if (tid < 64) cnts[tid] = ((const int*)ws)[W_CNT + tid];
      __syncthreads();
      const float4* cl4 = (const float4*)(ws + W_CL4);
      float t[5] = {BIGV, BIGV, BIGV, BIGV, BIGV};
      for (int seg = 0; seg < 64; ++seg) {
        int c = cnts[seg];
        for (int i = tid; i < c; i += 256) {
          float4 e = cl4[seg * 1024 + i];
          float d0 = e.x - m0, d1 = e.y - m1, d2 = e.z - m2;
          float dd = sqrtf(fmaf(d0, d0, fmaf(d1, d1, d2 * d2)));
          float vv = dd * e.w;
          vv = (vv < EPSV) ? BIGV : vv;
          t5ins(t, vv);
        }
      }
#pragma unroll
      for (int k = 0; k < 5; ++k) sl[tid * 5 + k] = t[k];
      __syncthreads();
      for (int s = 128; s >= 1; s >>= 1) {
        if (tid < s) {
          float a[5], b[5], o[5];
#pragma unroll
          for (int k = 0; k < 5; ++k) { a[k] = sl[tid * 5 + k]; b[k] = sl[(tid + s) * 5 + k]; }
          merge5(a, b, o);
#pragma unroll
          for (int k = 0; k < 5; ++k) sl[tid * 5 + k] = o[k];
        }
        __syncthreads();
      }
      if (tid == 0) {
        float* dst = (r < 128) ? (out + O_NN + 5 * r) : (out + O_NNG);
#pragma unroll
        for (int k = 0; k < 5; ++k) dst[k] = sl[k];
      }
    } else {
      // ---- finalize ----
      float* gs = sbuf;          // 8
      float* srms = sbuf + 8;    // 128
      float* smx2 = sbuf + 136;  // 384
      float* wsum2 = sbuf + 520; // 2
      if (tid < 64) {
        float a0 = ws[W_BS + tid * 8 + 0], a1 = ws[W_BS + tid * 8 + 1];
        float a2 = ws[W_BS + tid * 8 + 2], a3 = ws[W_BS + tid * 8 + 3];
        float a4 = ws[W_BS + tid * 8 + 4], a5 = ws[W_BS + tid * 8 + 5];
        float a6 = ws[W_BS + tid * 8 + 6];
        a0 = wred(a0); a1 = wred(a1); a2 = wred(a2); a3 = wred(a3);
        a4 = wred(a4); a5 = wred(a5); a6 = wred(a6);
        if (tid == 0) {
          gs[0] = a0; gs[1] = a1; gs[2] = a2; gs[3] = a3;
          gs[4] = a4; gs[5] = a5; gs[6] = a6;
        }
      }
      __syncthreads();
      int p = tid;
      float rms = 0.f, m0 = 0.f, m1 = 0.f, m2 = 0.f;
      if (p < 128) {
        float A = gs[0], B0 = gs[1], B1 = gs[2], B2 = gs[3];
        float Cq = gs[4], Sq = gs[5];
        float sx0 = 0.f, sx1 = 0.f, sx2 = 0.f, sxx = 0.f, cnt = 0.f;
        for (int b = 0; b < 64; ++b) {
          const float* pp = ws + W_PP + b * 640;
          sx0 += pp[p]; sx1 += pp[128 + p]; sx2 += pp[256 + p];
          sxx += pp[384 + p]; cnt += pp[512 + p];
        }
        m0 = mx[3 * p]; m1 = mx[3 * p + 1]; m2 = mx[3 * p + 2];
        float mqv = mq[p];
        float mm = fmaf(m0, m0, fmaf(m1, m1, m2 * m2));
        float s1 = fmaxf(sxx - 2.f * (m0 * sx0 + m1 * sx1 + m2 * sx2) + mm * cnt, 0.f);
        rms = sqrtf(s1 / cnt);
        float s2 = fmaxf(A - 2.f * (m0 * B0 + m1 * B1 + m2 * B2) + mm * Cq, 0.f);
        float rmsq = sqrtf(mqv * mqv * s2 / (cnt * ((float)PP * Sq)));
        out[O_RMS + p] = rms; out[O_RMSQ + p] = rmsq; out[O_NP + p] = cnt;
        if (p == 0) {
          out[O_RMSG]  = sqrtf(gs[6] / (float)NN);
          out[O_RMSQG] = sqrtf(gs[0] / ((float)NN * Sq));
          out[O_NG]    = (float)NN;
        }
        srms[p] = rms;
        smx2[3 * p] = m0; smx2[3 * p + 1] = m1; smx2[3 * p + 2] = m2;
      }
      __syncthreads();
      if (p < 128) {
        float mr = 0.f;
        for (int j = 0; j < PP; ++j) {
          float d0 = m0 - smx2[3 * j], d1 = m1 - smx2[3 * j + 1], d2 = m2 - smx2[3 * j + 2];
          float M2 = fmaf(d0, d0, fmaf(d1, d1, d2 * d2));
          float rr = (M2 > 0.f) ? (rms + srms[j]) / M2 : 0.f;
          mr = fmaxf(mr, rr);
        }
        float sred = wred(mr);
        if ((p & 63) == 0) wsum2[p >> 6] = sred;
      }
      __syncthreads();
      if (tid == 0) out[O_DB] = (wsum2[0] + wsum2[1]) * (1.0f / 128.0f);
    }
  }
}

extern "C" void kernel_launch(void* const* d_in, const int* in_sizes, int n_in,
                              void* d_out, int out_size, void* d_ws, size_t ws_size,
                              hipStream_t stream) {
  const float* x  = (const float*)d_in[0];
  const float* q  = (const float*)d_in[1];
  const float* ic = (const float*)d_in[2];
  const float* mx = (const float*)d_in[5];
  const float* mq = (const float*)d_in[6];
  const int*   par = (const int*)d_in[8];
  float* out = (float*)d_out;
  float* ws = (float*)d_ws;

  hipLaunchKernelGGL(gA, dim3(1218), dim3(256), 0, stream,
                     x, q, ic, par, mx, mq, ws, out);
}

// Round 8
// 57.336 us; speedup vs baseline: 1.0827x; 1.0827x over previous
//
#include <hip/hip_runtime.h>

#define NN 65536
#define PP 128
#define EPSV 1e-8f
#define BIGV 999.0f

typedef float f32x4 __attribute__((ext_vector_type(4)));

// ---- output float offsets (return-order flattening) ----
#define O_RMS   0
#define O_RMSQ  128
#define O_NP    256
#define O_NN    384
#define O_RMSG  1024
#define O_RMSQG 1025
#define O_NG    1026
#define O_NNG   1027
#define O_DB    1032
#define O_NNODE 1033
#define O_DIST  66569
#define O_BEL   (66569 + 8388608)

// ---- workspace float offsets ----
#define W_BS   0                  // 64 blocks x 8: A,B0,B1,B2,Cq,Sq,Sxx,(pad)
#define W_PP   512                // 64 blocks x 640: sx0[128],sx1,sx2,sxx,cnt
#define W_CNT  41472              // 64 ints: per-block cond count
#define W_CL4  303680             // float4 x 65536: compacted x0,x1,x2,ic

__device__ inline float wred(float v) {
#pragma unroll
  for (int o = 32; o > 0; o >>= 1) v += __shfl_down(v, o, 64);
  return v;
}

__device__ inline void t5ins(float t[5], float v) {
  if (v < t[4]) {
    t[4] = v;
#pragma unroll
    for (int k = 4; k > 0; --k)
      if (t[k] < t[k - 1]) { float tm = t[k]; t[k] = t[k - 1]; t[k - 1] = tm; }
  }
}

__device__ inline void merge5(const float* a, const float* b, float* o) {
  int i = 0, j = 0;
#pragma unroll
  for (int k = 0; k < 5; ++k) {
    float av = a[i], bv = b[j];
    if (av <= bv) { o[k] = av; ++i; } else { o[k] = bv; ++j; }
  }
}

// kA: blocks 0..63 = node stats (partials + compaction);
//     blocks 64..1087 = edge writes (dist+belongs), direct global reads.
__global__ __launch_bounds__(256) void kA(const float* __restrict__ x,
                                          const float* __restrict__ q,
                                          const float* __restrict__ ic,
                                          const int* __restrict__ par,
                                          const float* __restrict__ mx,
                                          float* __restrict__ ws,
                                          float* __restrict__ out) {
  int tid = threadIdx.x, bx = blockIdx.x;
  if (bx < 64) {
    // ---- stat path ----
    __shared__ float ps[640];
    __shared__ float wsum[4][8];
    __shared__ int lcnt;
    int b = bx;
    for (int i = tid; i < 640; i += 256) ps[i] = 0.f;
    if (tid == 0) lcnt = 0;
    __syncthreads();
    float A = 0.f, B0 = 0.f, B1 = 0.f, B2 = 0.f, Cq = 0.f, Sq = 0.f, Sxx = 0.f;
    float4* cl4 = (float4*)(ws + W_CL4);
    int base = b * 1024;
#pragma unroll
    for (int it = 0; it < 4; ++it) {
      int n = base + it * 256 + tid;
      float x0 = x[3 * n], x1 = x[3 * n + 1], x2 = x[3 * n + 2];
      float qn = q[n], icn = ic[n];
      int pa = par[n];
      float xx = fmaf(x0, x0, fmaf(x1, x1, x2 * x2));
      float q2 = qn * qn;
      A = fmaf(q2, xx, A); B0 = fmaf(q2, x0, B0);
      B1 = fmaf(q2, x1, B1); B2 = fmaf(q2, x2, B2);
      Cq += q2; Sq += qn; Sxx += xx;
      atomicAdd(&ps[pa], x0);
      atomicAdd(&ps[128 + pa], x1);
      atomicAdd(&ps[256 + pa], x2);
      atomicAdd(&ps[384 + pa], xx);
      atomicAdd(&ps[512 + pa], 1.0f);
      if (icn != 0.0f) {
        int loc = atomicAdd(&lcnt, 1);
        cl4[base + loc] = make_float4(x0, x1, x2, icn);
      }
    }
    A = wred(A); B0 = wred(B0); B1 = wred(B1); B2 = wred(B2);
    Cq = wred(Cq); Sq = wred(Sq); Sxx = wred(Sxx);
    int w = tid >> 6, lane = tid & 63;
    if (lane == 0) {
      wsum[w][0] = A; wsum[w][1] = B0; wsum[w][2] = B1;
      wsum[w][3] = B2; wsum[w][4] = Cq; wsum[w][5] = Sq;
      wsum[w][6] = Sxx;
    }
    __syncthreads();
    if (tid < 7)
      ws[W_BS + b * 8 + tid] =
          wsum[0][tid] + wsum[1][tid] + wsum[2][tid] + wsum[3][tid];
    if (tid == 0) ((int*)ws)[W_CNT + b] = lcnt;
    for (int i = tid; i < 640; i += 256) ws[W_PP + b * 640 + i] = ps[i];
  } else {
    // ---- edge path: direct global reads, no LDS staging for x/par ----
    __shared__ float smx[24];
    int e = bx - 64;
    int ey = e >> 6, ex = e & 63;
    int p0 = ey * 8;
    if (tid < 24) smx[tid] = mx[p0 * 3 + tid];
    __syncthreads();
    int v = ex * 256 + tid;
    if (v < 16383) {
      int n0 = 3 + 4 * v;
      float xv[12];
#pragma unroll
      for (int j = 0; j < 12; ++j) xv[j] = x[3 * n0 + j];
      int pa0 = par[n0], pa1 = par[n0 + 1], pa2 = par[n0 + 2], pa3 = par[n0 + 3];
#pragma unroll
      for (int pi = 0; pi < 8; ++pi) {
        int p = p0 + pi;
        float m0 = smx[3 * pi], m1 = smx[3 * pi + 1], m2 = smx[3 * pi + 2];
        f32x4 d, bl;
        float d0, d1, d2;
        d0 = xv[0] - m0; d1 = xv[1] - m1; d2 = xv[2] - m2;
        d.x = sqrtf(fmaf(d0, d0, fmaf(d1, d1, d2 * d2)));
        d0 = xv[3] - m0; d1 = xv[4] - m1; d2 = xv[5] - m2;
        d.y = sqrtf(fmaf(d0, d0, fmaf(d1, d1, d2 * d2)));
        d0 = xv[6] - m0; d1 = xv[7] - m1; d2 = xv[8] - m2;
        d.z = sqrtf(fmaf(d0, d0, fmaf(d1, d1, d2 * d2)));
        d0 = xv[9] - m0; d1 = xv[10] - m1; d2 = xv[11] - m2;
        d.w = sqrtf(fmaf(d0, d0, fmaf(d1, d1, d2 * d2)));
        bl.x = (pa0 == p) ? 1.f : 0.f; bl.y = (pa1 == p) ? 1.f : 0.f;
        bl.z = (pa2 == p) ? 1.f : 0.f; bl.w = (pa3 == p) ? 1.f : 0.f;
        size_t ro = (size_t)p * NN + n0;
        __builtin_nontemporal_store(d,  (f32x4*)(out + O_DIST + ro));
        __builtin_nontemporal_store(bl, (f32x4*)(out + O_BEL + ro));
      }
    } else if (v == 16383) {
      // ragged: n = 0,1,2,65535
      int ns[4] = {0, 1, 2, 65535};
#pragma unroll
      for (int k = 0; k < 4; ++k) {
        int n = ns[k];
        float x0 = x[3 * n], x1 = x[3 * n + 1], x2 = x[3 * n + 2];
        int pa = par[n];
#pragma unroll
        for (int pi = 0; pi < 8; ++pi) {
          int p = p0 + pi;
          float m0 = smx[3 * pi], m1 = smx[3 * pi + 1], m2 = smx[3 * pi + 2];
          float d0 = x0 - m0, d1 = x1 - m1, d2 = x2 - m2;
          float dd = sqrtf(fmaf(d0, d0, fmaf(d1, d1, d2 * d2)));
          size_t ro = (size_t)p * NN + n;
          __builtin_nontemporal_store(dd, out + O_DIST + ro);
          __builtin_nontemporal_store((pa == p) ? 1.f : 0.f, out + O_BEL + ro);
        }
      }
    }
  }
}

// kB: blocks 0..128 = top5 rows (128=global); 129 = finalize; 130..193 = N_node.
__global__ __launch_bounds__(256) void kB(const float* __restrict__ mx,
                                          const float* __restrict__ mq,
                                          const float* __restrict__ ws,
                                          const int* __restrict__ par,
                                          float* __restrict__ out) {
  __shared__ __align__(16) float sb[1344];
  int tid = threadIdx.x;
  int r = blockIdx.x;
  if (r < 129) {
    int* cnts = (int*)sb;         // 64
    float* sl = sb + 64;          // 1280
    float m0 = 0.f, m1 = 0.f, m2 = 0.f;
    if (r < 128) { m0 = mx[3 * r]; m1 = mx[3 * r + 1]; m2 = mx[3 * r + 2]; }
    if (tid < 64) cnts[tid] = ((const int*)ws)[W_CNT + tid];
    __syncthreads();
    const float4* cl4 = (const float4*)(ws + W_CL4);
    float t[5] = {BIGV, BIGV, BIGV, BIGV, BIGV};
    for (int seg = 0; seg < 64; ++seg) {
      int c = cnts[seg];
      for (int i = tid; i < c; i += 256) {
        float4 e = cl4[seg * 1024 + i];
        float d0 = e.x - m0, d1 = e.y - m1, d2 = e.z - m2;
        float dd = sqrtf(fmaf(d0, d0, fmaf(d1, d1, d2 * d2)));
        float vv = dd * e.w;
        vv = (vv < EPSV) ? BIGV : vv;
        t5ins(t, vv);
      }
    }
#pragma unroll
    for (int k = 0; k < 5; ++k) sl[tid * 5 + k] = t[k];
    __syncthreads();
    for (int s = 128; s >= 1; s >>= 1) {
      if (tid < s) {
        float a[5], b[5], o[5];
#pragma unroll
        for (int k = 0; k < 5; ++k) { a[k] = sl[tid * 5 + k]; b[k] = sl[(tid + s) * 5 + k]; }
        merge5(a, b, o);
#pragma unroll
        for (int k = 0; k < 5; ++k) sl[tid * 5 + k] = o[k];
      }
      __syncthreads();
    }
    if (tid == 0) {
      float* dst = (r < 128) ? (out + O_NN + 5 * r) : (out + O_NNG);
#pragma unroll
      for (int k = 0; k < 5; ++k) dst[k] = sl[k];
    }
  } else if (r == 129) {
    // finalize
    float* gs = sb;          // 8
    float* srms = sb + 8;    // 128
    float* smx2 = sb + 136;  // 384
    float* wsum2 = sb + 520; // 2
    if (tid < 64) {
      float a0 = ws[W_BS + tid * 8 + 0], a1 = ws[W_BS + tid * 8 + 1];
      float a2 = ws[W_BS + tid * 8 + 2], a3 = ws[W_BS + tid * 8 + 3];
      float a4 = ws[W_BS + tid * 8 + 4], a5 = ws[W_BS + tid * 8 + 5];
      float a6 = ws[W_BS + tid * 8 + 6];
      a0 = wred(a0); a1 = wred(a1); a2 = wred(a2); a3 = wred(a3);
      a4 = wred(a4); a5 = wred(a5); a6 = wred(a6);
      if (tid == 0) {
        gs[0] = a0; gs[1] = a1; gs[2] = a2; gs[3] = a3;
        gs[4] = a4; gs[5] = a5; gs[6] = a6;
      }
    }
    __syncthreads();
    int p = tid;
    float rms = 0.f, m0 = 0.f, m1 = 0.f, m2 = 0.f;
    if (p < 128) {
      float A = gs[0], B0 = gs[1], B1 = gs[2], B2 = gs[3];
      float Cq = gs[4], Sq = gs[5];
      float sx0 = 0.f, sx1 = 0.f, sx2 = 0.f, sxx = 0.f, cnt = 0.f;
      for (int b = 0; b < 64; ++b) {
        const float* pp = ws + W_PP + b * 640;
        sx0 += pp[p]; sx1 += pp[128 + p]; sx2 += pp[256 + p];
        sxx += pp[384 + p]; cnt += pp[512 + p];
      }
      m0 = mx[3 * p]; m1 = mx[3 * p + 1]; m2 = mx[3 * p + 2];
      float mqv = mq[p];
      float mm = fmaf(m0, m0, fmaf(m1, m1, m2 * m2));
      float s1 = fmaxf(sxx - 2.f * (m0 * sx0 + m1 * sx1 + m2 * sx2) + mm * cnt, 0.f);
      rms = sqrtf(s1 / cnt);
      float s2 = fmaxf(A - 2.f * (m0 * B0 + m1 * B1 + m2 * B2) + mm * Cq, 0.f);
      float rmsq = sqrtf(mqv * mqv * s2 / (cnt * ((float)PP * Sq)));
      out[O_RMS + p] = rms; out[O_RMSQ + p] = rmsq; out[O_NP + p] = cnt;
      if (p == 0) {
        out[O_RMSG]  = sqrtf(gs[6] / (float)NN);
        out[O_RMSQG] = sqrtf(gs[0] / ((float)NN * Sq));
        out[O_NG]    = (float)NN;
      }
      srms[p] = rms;
      smx2[3 * p] = m0; smx2[3 * p + 1] = m1; smx2[3 * p + 2] = m2;
    }
    __syncthreads();
    if (p < 128) {
      float mr = 0.f;
      for (int j = 0; j < PP; ++j) {
        float d0 = m0 - smx2[3 * j], d1 = m1 - smx2[3 * j + 1], d2 = m2 - smx2[3 * j + 2];
        float M2 = fmaf(d0, d0, fmaf(d1, d1, d2 * d2));
        float rr = (M2 > 0.f) ? (rms + srms[j]) / M2 : 0.f;
        mr = fmaxf(mr, rr);
      }
      float sred = wred(mr);
      if ((p & 63) == 0) wsum2[p >> 6] = sred;
    }
    __syncthreads();
    if (tid == 0) out[O_DB] = (wsum2[0] + wsum2[1]) * (1.0f / 128.0f);
  } else {
    // N_node
    float* snp = sb;   // 128
    if (tid < 128) {
      float s = 0.f;
      for (int b = 0; b < 64; ++b) s += ws[W_PP + b * 640 + 512 + tid];
      snp[tid] = s;
    }
    __syncthreads();
    int r2 = r - 130;
    int v = r2 * 256 + tid;
    if (v < 16383) {
      int n0 = 3 + 4 * v;
      f32x4 o = {snp[par[n0]], snp[par[n0 + 1]], snp[par[n0 + 2]], snp[par[n0 + 3]]};
      __builtin_nontemporal_store(o, (f32x4*)(out + O_NNODE + n0));
    } else if (v == 16383) {
      int ns[4] = {0, 1, 2, 65535};
#pragma unroll
      for (int k = 0; k < 4; ++k)
        __builtin_nontemporal_store(snp[par[ns[k]]], out + O_NNODE + ns[k]);
    }
  }
}

extern "C" void kernel_launch(void* const* d_in, const int* in_sizes, int n_in,
                              void* d_out, int out_size, void* d_ws, size_t ws_size,
                              hipStream_t stream) {
  const float* x  = (const float*)d_in[0];
  const float* q  = (const float*)d_in[1];
  const float* ic = (const float*)d_in[2];
  const float* mx = (const float*)d_in[5];
  const float* mq = (const float*)d_in[6];
  const int*   par = (const int*)d_in[8];
  float* out = (float*)d_out;
  float* ws = (float*)d_ws;

  hipLaunchKernelGGL(kA, dim3(1088), dim3(256), 0, stream, x, q, ic, par, mx, ws, out);
  hipLaunchKernelGGL(kB, dim3(194),  dim3(256), 0, stream, mx, mq, ws, par, out);
}